// Round 6
// baseline (421.267 us; speedup 1.0000x reference)
//
#include <hip/hip_runtime.h>

#define NN 16384
#define NCB 8
#define DIM 32
#define CB 1024

// Kernel A: csqb[k*CB+c] = ||codebook[k,c]||^2 + rate_bias[k,c]
__global__ __launch_bounds__(256) void vq_csq(const float* __restrict__ cb,
                                              const float* __restrict__ rb,
                                              float* __restrict__ out) {
    int i = blockIdx.x * 256 + threadIdx.x;
    if (i >= NCB * CB) return;
    const float4* c4 = reinterpret_cast<const float4*>(cb + (size_t)i * DIM);
    float s0 = 0.f, s1 = 0.f, s2 = 0.f, s3 = 0.f;
#pragma unroll
    for (int j = 0; j < 8; ++j) {
        float4 v = c4[j];
        s0 = fmaf(v.x, v.x, s0);
        s1 = fmaf(v.y, v.y, s1);
        s2 = fmaf(v.z, v.z, s2);
        s3 = fmaf(v.w, v.w, s3);
    }
    out[i] = ((s0 + s1) + (s2 + s3)) + rb[i];
}

// Frozen distance chain (identical op order to rounds 2-5; do not touch).
#define DOROW(XV, BD, BI, CQV, CGLOB)                                   \
    {                                                                   \
        float d0 = 0.f, d1 = 0.f, d2 = 0.f, d3 = 0.f;                   \
        d0 = fmaf(XV[0].x, a0.x, d0); d1 = fmaf(XV[0].y, a0.y, d1);     \
        d2 = fmaf(XV[0].z, a0.z, d2); d3 = fmaf(XV[0].w, a0.w, d3);     \
        d0 = fmaf(XV[1].x, a1.x, d0); d1 = fmaf(XV[1].y, a1.y, d1);     \
        d2 = fmaf(XV[1].z, a1.z, d2); d3 = fmaf(XV[1].w, a1.w, d3);     \
        d0 = fmaf(XV[2].x, a2.x, d0); d1 = fmaf(XV[2].y, a2.y, d1);     \
        d2 = fmaf(XV[2].z, a2.z, d2); d3 = fmaf(XV[2].w, a2.w, d3);     \
        d0 = fmaf(XV[3].x, a3.x, d0); d1 = fmaf(XV[3].y, a3.y, d1);     \
        d2 = fmaf(XV[3].z, a3.z, d2); d3 = fmaf(XV[3].w, a3.w, d3);     \
        d0 = fmaf(XV[4].x, a4.x, d0); d1 = fmaf(XV[4].y, a4.y, d1);     \
        d2 = fmaf(XV[4].z, a4.z, d2); d3 = fmaf(XV[4].w, a4.w, d3);     \
        d0 = fmaf(XV[5].x, a5.x, d0); d1 = fmaf(XV[5].y, a5.y, d1);     \
        d2 = fmaf(XV[5].z, a5.z, d2); d3 = fmaf(XV[5].w, a5.w, d3);     \
        d0 = fmaf(XV[6].x, a6.x, d0); d1 = fmaf(XV[6].y, a6.y, d1);     \
        d2 = fmaf(XV[6].z, a6.z, d2); d3 = fmaf(XV[6].w, a6.w, d3);     \
        d0 = fmaf(XV[7].x, a7.x, d0); d1 = fmaf(XV[7].y, a7.y, d1);     \
        d2 = fmaf(XV[7].z, a7.z, d2); d3 = fmaf(XV[7].w, a7.w, d3);     \
        const float dot = (d0 + d1) + (d2 + d3);                        \
        const float dist = fmaf(-2.f, dot, xsq_##XV + (CQV));           \
        if (dist < (BD)) { (BD) = dist; (BI) = (CGLOB); }               \
    }

// Fused kernel, dual-pipe broadcast scan. 1024 blocks x 1 wave (64 thr).
// Block = one k, 128 rows (2/lane). Per super-iter s (c-tiles 2s, 2s+1):
//   - prefetch odd tile -> regs (VMEM, hides under zeros+even compute)
//   - zero 16 one_hot rows (stores drain in background; in-order vmcnt
//     counting means later load-waits never drain them)
//   - even tile: direct wave-uniform vector loads (VMEM/L1 pipe)
//   - ds_write staged tile, odd tile from LDS (LDS pipe)
// Two broadcast pipes each carry half the 12-cyc/instr load -> scan ~2x
// round 3. No barriers anywhere: one_hot rows belong to this wave alone;
// a single s_waitcnt vmcnt(0) orders zeros before the 1.0 scatter.
__global__ __launch_bounds__(64) void vq_fused(const float* __restrict__ x,
                                               const float* __restrict__ cb,
                                               const float* __restrict__ csqb,
                                               float* __restrict__ xhat,
                                               float* __restrict__ onehot,
                                               float* __restrict__ idxf) {
    __shared__ float4 tb[64 * 8];  // 8 KB: one staged tile (same-wave ordered)

    const int lane = threadIdx.x;
    const int k = blockIdx.x & (NCB - 1);
    const int n0 = (blockIdx.x >> 3) * 128;
    const int r0 = n0 + lane;
    const int r1 = n0 + 64 + lane;

    const float4* cbk4 =
        reinterpret_cast<const float4*>(cb + (size_t)k * CB * DIM);
    const float* cqk = csqb + (size_t)k * CB;

    // x rows -> registers; ||x||^2 (frozen chain order)
    float4 xa[8], xb[8];
    {
        const float4* p0 =
            reinterpret_cast<const float4*>(x + ((size_t)r0 * NCB + k) * DIM);
        const float4* p1 =
            reinterpret_cast<const float4*>(x + ((size_t)r1 * NCB + k) * DIM);
#pragma unroll
        for (int j = 0; j < 8; ++j) { xa[j] = p0[j]; xb[j] = p1[j]; }
    }
    float xsq_xa, xsq_xb;
    {
        float q0 = 0.f, q1 = 0.f, q2 = 0.f, q3 = 0.f;
#pragma unroll
        for (int j = 0; j < 8; ++j) {
            q0 = fmaf(xa[j].x, xa[j].x, q0);
            q1 = fmaf(xa[j].y, xa[j].y, q1);
            q2 = fmaf(xa[j].z, xa[j].z, q2);
            q3 = fmaf(xa[j].w, xa[j].w, q3);
        }
        xsq_xa = (q0 + q1) + (q2 + q3);
        q0 = q1 = q2 = q3 = 0.f;
#pragma unroll
        for (int j = 0; j < 8; ++j) {
            q0 = fmaf(xb[j].x, xb[j].x, q0);
            q1 = fmaf(xb[j].y, xb[j].y, q1);
            q2 = fmaf(xb[j].z, xb[j].z, q2);
            q3 = fmaf(xb[j].w, xb[j].w, q3);
        }
        xsq_xb = (q0 + q1) + (q2 + q3);
    }

    float bda = 3.4028235e38f, bdb = 3.4028235e38f;
    int bia = 0, bib = 0;

    float4* oh4 = reinterpret_cast<float4*>(onehot);
    const float4 z4 = make_float4(0.f, 0.f, 0.f, 0.f);

    for (int s = 0; s < 8; ++s) {
        // prefetch odd tile (2s+1) into registers
        float4 st[8];
#pragma unroll
        for (int i = 0; i < 8; ++i)
            st[i] = cbk4[(size_t)(2 * s + 1) * 512 + i * 64 + lane];
        const float cql_e = cqk[2 * s * 64 + lane];
        const float cql_o = cqk[2 * s * 64 + 64 + lane];

        // zero 16 one_hot rows (this wave's rows only)
        {
            const int rbase = n0 + s * 16;
#pragma unroll
            for (int rr = 0; rr < 16; ++rr) {
                float4* rp = oh4 + ((size_t)(rbase + rr) * NCB + k) * 256;
#pragma unroll
                for (int j = 0; j < 4; ++j) rp[j * 64 + lane] = z4;
            }
        }

        // ---- even tile 2s: direct wave-uniform loads (VMEM pipe) ----
#pragma unroll 2
        for (int cc = 0; cc < 64; ++cc) {
            const float4* e = cbk4 + (size_t)(2 * s) * 512 + (size_t)cc * 8;
            const float4 a0 = e[0], a1 = e[1], a2 = e[2], a3 = e[3];
            const float4 a4 = e[4], a5 = e[5], a6 = e[6], a7 = e[7];
            const float cqv = __int_as_float(
                __builtin_amdgcn_readlane(__float_as_int(cql_e), cc));
            const int cg = s * 128 + cc;
            DOROW(xa, bda, bia, cqv, cg)
            DOROW(xb, bdb, bib, cqv, cg)
        }

        // ---- odd tile 2s+1: stage to LDS, compute (LDS pipe) ----
#pragma unroll
        for (int i = 0; i < 8; ++i) tb[i * 64 + lane] = st[i];
        // same-wave ds ordering: no barrier needed
#pragma unroll 2
        for (int cc = 0; cc < 64; ++cc) {
            const float4* e = &tb[cc * 8];
            const float4 a0 = e[0], a1 = e[1], a2 = e[2], a3 = e[3];
            const float4 a4 = e[4], a5 = e[5], a6 = e[6], a7 = e[7];
            const float cqv = __int_as_float(
                __builtin_amdgcn_readlane(__float_as_int(cql_o), cc));
            const int cg = s * 128 + 64 + cc;
            DOROW(xa, bda, bia, cqv, cg)
            DOROW(xb, bdb, bib, cqv, cg)
        }
    }

    // order this wave's zero-stores before its 1.0 scatters (same addresses)
    asm volatile("s_waitcnt vmcnt(0)" ::: "memory");

    // epilogue: index / x_hat / one_hot scatter for both rows
    {
        idxf[(size_t)r0 * NCB + k] = (float)bia;
        const float4* src = cbk4 + (size_t)bia * 8;
        float4* dst =
            reinterpret_cast<float4*>(xhat + ((size_t)r0 * NCB + k) * DIM);
#pragma unroll
        for (int j = 0; j < 8; ++j) dst[j] = src[j];
        onehot[((size_t)r0 * NCB + k) * CB + bia] = 1.0f;
    }
    {
        idxf[(size_t)r1 * NCB + k] = (float)bib;
        const float4* src = cbk4 + (size_t)bib * 8;
        float4* dst =
            reinterpret_cast<float4*>(xhat + ((size_t)r1 * NCB + k) * DIM);
#pragma unroll
        for (int j = 0; j < 8; ++j) dst[j] = src[j];
        onehot[((size_t)r1 * NCB + k) * CB + bib] = 1.0f;
    }
}

extern "C" void kernel_launch(void* const* d_in, const int* in_sizes, int n_in,
                              void* d_out, int out_size, void* d_ws,
                              size_t ws_size, hipStream_t stream) {
    const float* x = (const float*)d_in[0];
    const float* cb = (const float*)d_in[1];
    const float* rb = (const float*)d_in[2];

    float* out = (float*)d_out;
    float* xhat = out;                             // N*NCB*DIM
    float* onehot = out + (size_t)NN * NCB * DIM;  // N*NCB*CB
    float* idxf = onehot + (size_t)NN * NCB * CB;  // N*NCB

    float* csqb = (float*)d_ws;  // NCB*CB floats = 32 KB

    vq_csq<<<(NCB * CB + 255) / 256, 256, 0, stream>>>(cb, rb, csqb);
    vq_fused<<<(NN / 128) * NCB, 64, 0, stream>>>(x, cb, csqb, xhat, onehot,
                                                  idxf);
}